// Round 9
// baseline (225.708 us; speedup 1.0000x reference)
//
#include <hip/hip_runtime.h>

// Problem constants (from reference setup_inputs)
#define BB   64          // batch
#define SS   512         // seq len
#define HH   768         // hidden dim
#define WW   256         // MAX_WORD_LEN (words per batch)
#define WE   300         // word-embedding dim
#define OUTD (HH + WE)   // 1068 output feature dim
#define LBS  (WW + 1)    // bounds-table stride per batch row (257)

#define OUT_F4   ((BB * WW * OUTD) / 4)   // out size in float4 = 4,374,528

// R9 = R8 champion (62us) + ATTRIBUTION PROBE. After 8 rounds every theory
// (search latency, MLP, occupancy, DMA) is falsified: our work is pinned at
// ~62-73us / 2.1 TB/s under all structures while the harness fill does 6.6.
// Missing datapoint: a PURE STREAMING kernel on these same buffers in this
// same harness. The probe (grid-stride float4 copy hidden->out, 70+70 MB,
// 4-deep batched) runs FIRST; the real kernels then overwrite every byte of
// out, so correctness is preserved and the probe's own rocprof row gives the
// in-harness streaming ceiling. Decision next round:
//   probe >=5 TB/s  -> cap is structural to the op  -> keep attacking
//   probe ~2-3 TB/s -> cap is environmental -> we are at effective roofline

// ---------------- probe: pure streaming copy (overwritten later) ----------
__global__ __launch_bounds__(256)
void EmbeddingsModule_45311904973549_probe_copy(
    const float4* __restrict__ src,   // hidden, first OUT_F4 float4s
    float4*       __restrict__ dst)   // out
{
    const int    step = gridDim.x * 256 * 4;
    for (size_t i = (size_t)blockIdx.x * 1024 + threadIdx.x * 4;
         i + 3 < OUT_F4; i += step) {
        float4 v0 = src[i + 0];
        float4 v1 = src[i + 1];
        float4 v2 = src[i + 2];
        float4 v3 = src[i + 3];
        dst[i + 0] = v0;
        dst[i + 1] = v1;
        dst[i + 2] = v2;
        dst[i + 3] = v3;
    }
}

// ---------------- kernel A: per-(b,w) lower bounds -> d_ws ----------------
__global__ __launch_bounds__(256)
void EmbeddingsModule_45311904973549_bounds(
    const int* __restrict__ token_ids,   // [B, S] sorted per row, in [0,W)
    int*       __restrict__ LBg)         // [B, 257]
{
    __shared__ int tk[SS];
    __shared__ int LB[LBS];

    const int b   = blockIdx.x;
    const int tid = threadIdx.x;

    ((int2*)tk)[tid] = ((const int2*)(token_ids + (size_t)b * SS))[tid];
    LB[tid] = SS;
    if (tid == 0) LB[WW] = SS;
    __syncthreads();

    // scatter: position s with t=tk[s], tp=tk[s-1] (tp=-1 at s=0) sets
    // LB[k]=s for k in (tp, t]; ranges are disjoint across s -> no race.
    #pragma unroll
    for (int u = 0; u < 2; ++u) {
        const int s  = tid * 2 + u;
        const int t  = tk[s];
        const int tp = (s == 0) ? -1 : tk[s - 1];
        for (int k = tp + 1; k <= t; ++k) LB[k] = s;
    }
    __syncthreads();

    LBg[b * LBS + tid] = LB[tid];
    if (tid == 0) LBg[b * LBS + WW] = LB[WW];
}

// ------------- kernel B: R0 structure, bounds from table ------------------
__global__ __launch_bounds__(256)
void EmbeddingsModule_45311904973549_kernel(
    const float* __restrict__ hidden,     // [B, S, H]
    const float* __restrict__ w2v,        // [VOCAB, WE]
    const int*   __restrict__ LBg,        // [B, 257] lower bounds
    const int*   __restrict__ word_ids,   // [B, W] in [0,VOCAB)
    float*       __restrict__ out)        // [B, W, OUTD]
{
    const int bw  = blockIdx.x;       // 0 .. B*W-1
    const int b   = bw >> 8;          // / WW
    const int w   = bw & (WW - 1);    // % WW
    const int tid = threadIdx.x;

    float* orow = out + (size_t)bw * OUTD;

    if (tid < 192) {
        // two independent scalar loads (uniform address -> s_load), no chain
        const int lo = LBg[b * LBS + w];
        const int hi = LBg[b * LBS + w + 1];
        const int cnt = hi - lo;
        const float inv = (cnt > 0) ? (1.0f / (float)cnt) : 0.0f;

        const float4* hrow = (const float4*)(hidden + (size_t)b * SS * HH);
        float4 acc = make_float4(0.f, 0.f, 0.f, 0.f);
        int s = lo;
        for (; s + 1 < hi; s += 2) {
            // both loads independent (issue together); adds sequential so
            // summation order == reference (absmax back to 0)
            float4 v0 = hrow[(size_t)s       * (HH / 4) + tid];
            float4 v1 = hrow[(size_t)(s + 1) * (HH / 4) + tid];
            acc.x += v0.x; acc.y += v0.y; acc.z += v0.z; acc.w += v0.w;
            acc.x += v1.x; acc.y += v1.y; acc.z += v1.z; acc.w += v1.w;
        }
        if (s < hi) {
            float4 v0 = hrow[(size_t)s * (HH / 4) + tid];
            acc.x += v0.x; acc.y += v0.y; acc.z += v0.z; acc.w += v0.w;
        }
        acc.x *= inv; acc.y *= inv; acc.z *= inv; acc.w *= inv;
        ((float4*)orow)[tid] = acc;     // out[b,w, 0:768]
    } else {
        // w2v gather: 75 float4s with 64 threads (j and j+64)
        const int     wid  = word_ids[bw];
        const float4* wrow = (const float4*)(w2v + (size_t)wid * WE);
        float4*       grow = (float4*)(orow + HH);   // out[b,w, 768:1068]
        for (int j = tid - 192; j < WE / 4; j += 64) {
            grow[j] = wrow[j];
        }
    }
}

extern "C" void kernel_launch(void* const* d_in, const int* in_sizes, int n_in,
                              void* d_out, int out_size, void* d_ws, size_t ws_size,
                              hipStream_t stream) {
    const float* hidden    = (const float*)d_in[0];
    const float* w2v       = (const float*)d_in[1];
    const int*   token_ids = (const int*)d_in[2];
    const int*   word_ids  = (const int*)d_in[3];
    float*       out       = (float*)d_out;
    int*         LBg       = (int*)d_ws;    // 64*257*4 = 65,792 B

    // attribution probe first (its output is fully overwritten below)
    EmbeddingsModule_45311904973549_probe_copy<<<2048, 256, 0, stream>>>(
        (const float4*)hidden, (float4*)out);

    EmbeddingsModule_45311904973549_bounds<<<BB, 256, 0, stream>>>(
        token_ids, LBg);
    EmbeddingsModule_45311904973549_kernel<<<BB * WW, 256, 0, stream>>>(
        hidden, w2v, LBg, word_ids, out);
}